// Round 5
// baseline (5349.146 us; speedup 1.0000x reference)
//
#include <hip/hip_runtime.h>

#define NPIX (512 * 512)
#define NSTEPS 128
#define SRC 96
#define NOUTT (NSTEPS - SRC)          // 32
#define OSTRIDE ((size_t)NOUTT * NPIX)  // per-field output stride (floats)

__device__ __forceinline__ float softplus_f(float z) {
    // jax.nn.softplus = max(z,0) + log1p(exp(-|z|))
    return fmaxf(z, 0.0f) + log1pf(expf(-fabsf(z)));
}

__device__ __forceinline__ void phys_step(
    float p, float tm, float pe, float la,
    float& sn, float& ic, float& so, float& gw,
    const float* __restrict__ sW, const float* __restrict__ sb,
    float& tot, float& q1o, float& q2o, float& q3o, float& aeto)
{
    float rain = (tm > 0.0f) ? p : 0.0f;
    sn += p - rain;
    float water = rain;
    float ovf = fmaxf(ic + water - 2.0f, 0.0f);      // MAX_INT = 2.0
    ic += water - ovf;
    water = ovf;
    float melt = fminf(fmaxf(tm, 0.0f) * 3.0f, sn);  // MELT_RATE = 3.0
    sn -= melt;
    water += melt;

    const float xv[8] = {water, pe, la, tm, sn, ic, so, gw};
    float f[7];
#pragma unroll
    for (int k = 0; k < 7; ++k) {
        float z = sb[k];
#pragma unroll
        for (int c = 0; c < 8; ++c) z += xv[c] * sW[k * 8 + c];
        f[k] = softplus_f(z);
    }
    float aet = f[0], inf = f[1], per = f[2], cap = f[3];
    float q1 = f[4], q2 = f[5], q3 = f[6];

    float avail = ic + water;
    aet = fminf(aet, avail * pe);
    inf = fminf(inf, avail - aet);
    float d0 = avail + 1e-8f;
    ic    -= aet * (ic / d0);
    water -= aet * (water / d0);
    float d1 = avail - aet + 1e-8f;
    ic    -= inf * (ic / d1);
    water -= inf * (water / d1);
    per = fminf(per, so);
    cap = fminf(cap, so);
    so += inf - per - cap;
    gw += per;
    q1 = fminf(q1, water);
    q2 = fminf(q2, so);
    q3 = fminf(q3, gw);
    so -= q2;
    gw -= q3;
    tot = q1 + q2 + q3;
    sn = fmaxf(sn, 0.0f);
    ic = fmaxf(ic, 0.0f);
    so = fmaxf(so, 0.0f);
    gw = fmaxf(gw, 0.0f);
    q1o = q1; q2o = q2; q3o = q3; aeto = aet;
}

// K1: full physics scan. Writes fields 0 (Q), 2..5 (q1,q2,q3,aet) and SEEDS
// field 6 with tot (the identity term of the routing polynomial). 512x256,
// 2 consecutive pixels per thread, float2 loads/stores. Plain launch.
__global__ void __launch_bounds__(256)
physics_kernel(const float* __restrict__ prec,
               const float* __restrict__ temp_,
               const float* __restrict__ pet_,
               const float* __restrict__ lai_,
               const float* __restrict__ Wf,
               const float* __restrict__ bf,
               float* __restrict__ out)
{
    const int tid = blockIdx.x * 256 + threadIdx.x;   // 0..131071
    const int pix0 = tid * 2;

    __shared__ float sW[56];
    __shared__ float sb[7];
    if (threadIdx.x < 56) sW[threadIdx.x] = Wf[threadIdx.x];
    if (threadIdx.x < 7)  sb[threadIdx.x] = bf[threadIdx.x];
    __syncthreads();

    float sn[2] = {0.0f, 0.0f}, ic[2] = {0.0f, 0.0f};
    float so[2] = {50.0f, 50.0f}, gw[2] = {100.0f, 100.0f};

    for (int t = 0; t < NSTEPS; ++t) {
        const size_t off = (size_t)t * NPIX + pix0;
        const float2 p2 = *(const float2*)(prec  + off);
        const float2 t2 = *(const float2*)(temp_ + off);
        const float2 e2 = *(const float2*)(pet_  + off);
        const float2 l2 = *(const float2*)(lai_  + off);
        float tot[2], q1[2], q2[2], q3[2], aet[2];
        phys_step(p2.x, t2.x, e2.x, l2.x, sn[0], ic[0], so[0], gw[0], sW, sb,
                  tot[0], q1[0], q2[0], q3[0], aet[0]);
        phys_step(p2.y, t2.y, e2.y, l2.y, sn[1], ic[1], so[1], gw[1], sW, sb,
                  tot[1], q1[1], q2[1], q3[1], aet[1]);
        if (t >= SRC) {
            float* o = out + (size_t)(t - SRC) * NPIX + pix0;
            *(float2*)(o + 0 * OSTRIDE) = make_float2(tot[0], tot[1]);  // Q
            *(float2*)(o + 2 * OSTRIDE) = make_float2(q1[0], q1[1]);
            *(float2*)(o + 3 * OSTRIDE) = make_float2(q2[0], q2[1]);
            *(float2*)(o + 4 * OSTRIDE) = make_float2(q3[0], q3[1]);
            *(float2*)(o + 5 * OSTRIDE) = make_float2(aet[0], aet[1]);
            *(float2*)(o + 6 * OSTRIDE) = make_float2(tot[0], tot[1]);  // identity seed
        }
    }
}

// K2: scatter. routed = tot + sum_k coef_k S^k tot, with
// coef = [5,15,20,35,21,28,8,9,1,1] for S^1..S^10 (derived via the recurrence
// A_{n+1}=A_n+S*C_n, C_{n+1}=A_{n+1}-C_n from A_0=C_0=1; coefficient sum
// 144 = Fib_12 matches direct iteration). Field 6 already holds the identity
// term; this kernel adds the 10 scatter terms via plain device-scope
// atomicAdd. No cross-block reads inside this dispatch -> no coherence
// assumptions beyond basic atomics. One thread per source pixel.
__global__ void __launch_bounds__(256)
scatter_kernel(const int* __restrict__ fd, float* out)
{
    const int i = blockIdx.x * 256 + threadIdx.x;     // 0..262143

    // int64-vs-int32 staging detection (wave-uniform; P(false positive) ~ 2^-288)
    bool is64 = true;
#pragma unroll
    for (int k = 0; k < 16; ++k) is64 = is64 && (fd[2 * k + 1] == 0);

    int dest[10];
    int d = i;
#pragma unroll
    for (int k = 0; k < 10; ++k) {
        d = is64 ? fd[2 * d] : fd[d];
        d &= (NPIX - 1);              // OOB insurance (NPIX = 2^18)
        dest[k] = d;
    }

    const float coef[10] = {5.f, 15.f, 20.f, 35.f, 21.f, 28.f, 8.f, 9.f, 1.f, 1.f};
    const float* Q  = out;                 // field 0
    float*       RT = out + 6 * OSTRIDE;   // field 6 (seeded with tot by K1)

    for (int t = 0; t < NOUTT; ++t) {
        const float tv = Q[(size_t)t * NPIX + i];
#pragma unroll
        for (int k = 0; k < 10; ++k) {
            atomicAdd(&RT[(size_t)t * NPIX + dest[k]], coef[k] * tv);
        }
    }
}

// K3: field 1 (Q_routed) = copy of field 6 (total_runoff == Q_routed).
// 8192 blocks x 256 threads x float4 = exactly OSTRIDE elements.
__global__ void __launch_bounds__(256)
finalize_kernel(float* out)
{
    const size_t idx = ((size_t)blockIdx.x * 256 + threadIdx.x) * 4;
    const float4 r = *(const float4*)(out + 6 * OSTRIDE + idx);
    *(float4*)(out + 1 * OSTRIDE + idx) = r;
}

extern "C" void kernel_launch(void* const* d_in, const int* in_sizes, int n_in,
                              void* d_out, int out_size, void* d_ws, size_t ws_size,
                              hipStream_t stream)
{
    const float* prec  = (const float*)d_in[0];
    const float* temp_ = (const float*)d_in[1];
    const float* pet_  = (const float*)d_in[2];
    const float* lai_  = (const float*)d_in[3];
    const float* Wf    = (const float*)d_in[4];
    const float* bf    = (const float*)d_in[5];
    const int*   fd    = (const int*)d_in[6];
    float* out = (float*)d_out;

    physics_kernel<<<dim3(512), dim3(256), 0, stream>>>(prec, temp_, pet_, lai_, Wf, bf, out);
    scatter_kernel<<<dim3(1024), dim3(256), 0, stream>>>(fd, out);
    finalize_kernel<<<dim3(8192), dim3(256), 0, stream>>>(out);
}

// Round 6
// 3500.586 us; speedup vs baseline: 1.5281x; 1.5281x over previous
//
#include <hip/hip_runtime.h>

#define NPIX (512 * 512)
#define NSTEPS 128
#define SRC 96
#define NOUTT (NSTEPS - SRC)            // 32
#define OSTRIDE ((size_t)NOUTT * NPIX)  // per-field output stride (floats)
#define NENT (10 * NPIX)                // total CSR entries (exactly 10 per source)

__device__ __forceinline__ float softplus_f(float z) {
    return fmaxf(z, 0.0f) + log1pf(expf(-fabsf(z)));
}

__device__ __forceinline__ void phys_step(
    float p, float tm, float pe, float la,
    float& sn, float& ic, float& so, float& gw,
    const float* __restrict__ sW, const float* __restrict__ sb,
    float& tot, float& q1o, float& q2o, float& q3o, float& aeto)
{
    float rain = (tm > 0.0f) ? p : 0.0f;
    sn += p - rain;
    float water = rain;
    float ovf = fmaxf(ic + water - 2.0f, 0.0f);      // MAX_INT = 2.0
    ic += water - ovf;
    water = ovf;
    float melt = fminf(fmaxf(tm, 0.0f) * 3.0f, sn);  // MELT_RATE = 3.0
    sn -= melt;
    water += melt;

    const float xv[8] = {water, pe, la, tm, sn, ic, so, gw};
    float f[7];
#pragma unroll
    for (int k = 0; k < 7; ++k) {
        float z = sb[k];
#pragma unroll
        for (int c = 0; c < 8; ++c) z += xv[c] * sW[k * 8 + c];
        f[k] = softplus_f(z);
    }
    float aet = f[0], inf = f[1], per = f[2], cap = f[3];
    float q1 = f[4], q2 = f[5], q3 = f[6];

    float avail = ic + water;
    aet = fminf(aet, avail * pe);
    inf = fminf(inf, avail - aet);
    float d0 = avail + 1e-8f;
    ic    -= aet * (ic / d0);
    water -= aet * (water / d0);
    float d1 = avail - aet + 1e-8f;
    ic    -= inf * (ic / d1);
    water -= inf * (water / d1);
    per = fminf(per, so);
    cap = fminf(cap, so);
    so += inf - per - cap;
    gw += per;
    q1 = fminf(q1, water);
    q2 = fminf(q2, so);
    q3 = fminf(q3, gw);
    so -= q2;
    gw -= q3;
    tot = q1 + q2 + q3;
    sn = fmaxf(sn, 0.0f);
    ic = fmaxf(ic, 0.0f);
    so = fmaxf(so, 0.0f);
    gw = fmaxf(gw, 0.0f);
    q1o = q1; q2o = q2; q3o = q3; aeto = aet;
}

// K1: physics scan, 1 pixel/thread (4096 waves = 4 waves/SIMD, 2x the latency
// hiding of the 2px/thread version which ran at only 2 waves/SIMD).
__global__ void __launch_bounds__(256)
physics_kernel(const float* __restrict__ prec,
               const float* __restrict__ temp_,
               const float* __restrict__ pet_,
               const float* __restrict__ lai_,
               const float* __restrict__ Wf,
               const float* __restrict__ bf,
               float* __restrict__ out)
{
    const int i = blockIdx.x * 256 + threadIdx.x;   // 0..NPIX-1

    __shared__ float sW[56];
    __shared__ float sb[7];
    if (threadIdx.x < 56) sW[threadIdx.x] = Wf[threadIdx.x];
    if (threadIdx.x < 7)  sb[threadIdx.x] = bf[threadIdx.x];
    __syncthreads();

    float sn = 0.0f, ic = 0.0f, so = 50.0f, gw = 100.0f;

    for (int t = 0; t < NSTEPS; ++t) {
        const size_t off = (size_t)t * NPIX + i;
        float p  = prec[off];
        float tm = temp_[off];
        float pe = pet_[off];
        float la = lai_[off];
        float tot, q1, q2, q3, aet;
        phys_step(p, tm, pe, la, sn, ic, so, gw, sW, sb, tot, q1, q2, q3, aet);
        if (t >= SRC) {
            float* o = out + (size_t)(t - SRC) * NPIX + i;
            o[0 * OSTRIDE] = tot;   // Q
            o[2 * OSTRIDE] = q1;
            o[3 * OSTRIDE] = q2;
            o[4 * OSTRIDE] = q3;
            o[5 * OSTRIDE] = aet;
            o[6 * OSTRIDE] = tot;   // identity seed (used by scatter fallback)
        }
    }
}

// ---------- CSR build: reverse map of  A = I + sum_k coef[k] * S^(k+1) ----------
// coef[k] for S^(k+1), k=0..9; derived from A_{n+1}=A_n+S*C_n, C_{n+1}=A_{n+1}-C_n.
__global__ void __launch_bounds__(256)
zero_cnt(unsigned* __restrict__ cnt)
{
    cnt[blockIdx.x * 256 + threadIdx.x] = 0u;
}

__global__ void __launch_bounds__(256)
count_kernel(const int* __restrict__ fd, unsigned* __restrict__ cnt,
             unsigned* __restrict__ chains)
{
    const int i = blockIdx.x * 256 + threadIdx.x;
    // int64-vs-int32 staging detection (wave-uniform)
    bool is64 = true;
#pragma unroll
    for (int k = 0; k < 16; ++k) is64 = is64 && (fd[2 * k + 1] == 0);
    int d = i;
#pragma unroll
    for (int k = 0; k < 10; ++k) {
        d = is64 ? fd[2 * d] : fd[d];
        d &= (NPIX - 1);
        chains[k * NPIX + i] = (unsigned)d;   // coalesced per k-plane
        atomicAdd(&cnt[d], 1u);
    }
}

__global__ void __launch_bounds__(256)
scan1(const unsigned* __restrict__ cnt, unsigned* __restrict__ ofs,
      unsigned* __restrict__ blk)
{
    __shared__ unsigned s[256];
    const int tid = threadIdx.x;
    const int g = blockIdx.x * 256 + tid;
    const unsigned v = cnt[g];
    s[tid] = v;
    __syncthreads();
    for (int off = 1; off < 256; off <<= 1) {
        unsigned x = (tid >= off) ? s[tid - off] : 0u;
        __syncthreads();
        s[tid] += x;
        __syncthreads();
    }
    ofs[g] = s[tid] - v;                 // exclusive within block
    if (tid == 255) blk[blockIdx.x] = s[255];
}

__global__ void __launch_bounds__(256)
scan2(unsigned* __restrict__ blk)       // scans 1024 block totals in place
{
    __shared__ unsigned s[256];
    const int tid = threadIdx.x;
    unsigned l0 = blk[tid * 4 + 0], l1 = blk[tid * 4 + 1];
    unsigned l2 = blk[tid * 4 + 2], l3 = blk[tid * 4 + 3];
    unsigned sum = l0 + l1 + l2 + l3;
    s[tid] = sum;
    __syncthreads();
    for (int off = 1; off < 256; off <<= 1) {
        unsigned x = (tid >= off) ? s[tid - off] : 0u;
        __syncthreads();
        s[tid] += x;
        __syncthreads();
    }
    unsigned run = s[tid] - sum;         // exclusive base for this thread's 4
    blk[tid * 4 + 0] = run; run += l0;
    blk[tid * 4 + 1] = run; run += l1;
    blk[tid * 4 + 2] = run; run += l2;
    blk[tid * 4 + 3] = run;
}

__global__ void __launch_bounds__(256)
scan3(unsigned* __restrict__ ofs, const unsigned* __restrict__ blk,
      unsigned* __restrict__ cur)
{
    const int g = blockIdx.x * 256 + threadIdx.x;
    const unsigned o = ofs[g] + blk[blockIdx.x];
    ofs[g] = o;
    cur[g] = o;
    if (g == 0) ofs[NPIX] = NENT;
}

__global__ void __launch_bounds__(256)
fill_kernel(const unsigned* __restrict__ chains, unsigned* __restrict__ cur,
            unsigned* __restrict__ entries)
{
    const int i = blockIdx.x * 256 + threadIdx.x;
#pragma unroll
    for (int k = 0; k < 10; ++k) {
        const unsigned d = chains[k * NPIX + i];
        const unsigned pos = atomicAdd(&cur[d], 1u);
        entries[pos] = ((unsigned)i << 4) | (unsigned)k;   // src(18b) | coefIdx(4b)
    }
}

// Gather: routed[t][o] = Q[t][o] + sum_entries coef[k] * Q[t][src].
// Zero hot-path atomics; per-t Q slice (1 MB) and per-XCD entry share are
// L2-resident. Two t per pass: halves entry re-reads, working set < 4 MB/XCD.
__global__ void __launch_bounds__(256)
gather_kernel(const unsigned* __restrict__ ofs, const unsigned* __restrict__ entries,
              float* __restrict__ out)
{
    __shared__ float scoef[16];
    if (threadIdx.x < 16) {
        const float c[16] = {5.f,15.f,20.f,35.f,21.f,28.f,8.f,9.f,1.f,1.f,
                             0.f,0.f,0.f,0.f,0.f,0.f};
        scoef[threadIdx.x] = c[threadIdx.x];
    }
    __syncthreads();

    const int o = blockIdx.x * 256 + threadIdx.x;
    const unsigned s0 = ofs[o], s1 = ofs[o + 1];
    const float* Q  = out;                 // field 0
    float*       R1 = out + 1 * OSTRIDE;   // Q_routed
    float*       R6 = out + 6 * OSTRIDE;   // total_runoff

    for (int t = 0; t < NOUTT; t += 2) {
        const float* Q0 = Q + (size_t)t * NPIX;
        const float* Q1 = Q0 + NPIX;
        float a0 = Q0[o];                  // identity term
        float a1 = Q1[o];
        for (unsigned j = s0; j < s1; ++j) {
            const unsigned e = entries[j];
            const float c = scoef[e & 15u];
            const unsigned s = e >> 4;
            a0 += c * Q0[s];
            a1 += c * Q1[s];
        }
        R1[(size_t)t * NPIX + o] = a0;
        R1[(size_t)(t + 1) * NPIX + o] = a1;
        R6[(size_t)t * NPIX + o] = a0;
        R6[(size_t)(t + 1) * NPIX + o] = a1;
    }
}

// ---------- fallback path (proven correct in round 5) ----------
__global__ void __launch_bounds__(256)
scatter_kernel(const int* __restrict__ fd, float* out)
{
    const int i = blockIdx.x * 256 + threadIdx.x;
    bool is64 = true;
#pragma unroll
    for (int k = 0; k < 16; ++k) is64 = is64 && (fd[2 * k + 1] == 0);
    int dest[10];
    int d = i;
#pragma unroll
    for (int k = 0; k < 10; ++k) {
        d = is64 ? fd[2 * d] : fd[d];
        d &= (NPIX - 1);
        dest[k] = d;
    }
    const float coef[10] = {5.f, 15.f, 20.f, 35.f, 21.f, 28.f, 8.f, 9.f, 1.f, 1.f};
    const float* Q  = out;
    float*       RT = out + 6 * OSTRIDE;
    for (int t = 0; t < NOUTT; ++t) {
        const float tv = Q[(size_t)t * NPIX + i];
#pragma unroll
        for (int k = 0; k < 10; ++k)
            atomicAdd(&RT[(size_t)t * NPIX + dest[k]], coef[k] * tv);
    }
}

__global__ void __launch_bounds__(256)
finalize_kernel(float* out)
{
    const size_t idx = ((size_t)blockIdx.x * 256 + threadIdx.x) * 4;
    const float4 r = *(const float4*)(out + 6 * OSTRIDE + idx);
    *(float4*)(out + 1 * OSTRIDE + idx) = r;
}

extern "C" void kernel_launch(void* const* d_in, const int* in_sizes, int n_in,
                              void* d_out, int out_size, void* d_ws, size_t ws_size,
                              hipStream_t stream)
{
    const float* prec  = (const float*)d_in[0];
    const float* temp_ = (const float*)d_in[1];
    const float* pet_  = (const float*)d_in[2];
    const float* lai_  = (const float*)d_in[3];
    const float* Wf    = (const float*)d_in[4];
    const float* bf    = (const float*)d_in[5];
    const int*   fd    = (const int*)d_in[6];
    float* out = (float*)d_out;

    physics_kernel<<<dim3(1024), dim3(256), 0, stream>>>(prec, temp_, pet_, lai_, Wf, bf, out);

    // ws layout (u32): cnt[NPIX] | cur[NPIX] | ofs[NPIX+16] | blk[1024]
    //                  | chains[NENT] | entries[NENT]   ~= 23 MB
    const size_t need = (size_t)(NPIX * 3 + 16 + 1024 + 2 * NENT) * sizeof(unsigned);
    if (ws_size >= need) {
        unsigned* cnt     = (unsigned*)d_ws;
        unsigned* cur     = cnt + NPIX;
        unsigned* ofs     = cur + NPIX;
        unsigned* blk     = ofs + NPIX + 16;
        unsigned* chains  = blk + 1024;
        unsigned* entries = chains + NENT;

        zero_cnt    <<<dim3(1024), dim3(256), 0, stream>>>(cnt);
        count_kernel<<<dim3(1024), dim3(256), 0, stream>>>(fd, cnt, chains);
        scan1       <<<dim3(1024), dim3(256), 0, stream>>>(cnt, ofs, blk);
        scan2       <<<dim3(1),    dim3(256), 0, stream>>>(blk);
        scan3       <<<dim3(1024), dim3(256), 0, stream>>>(ofs, blk, cur);
        fill_kernel <<<dim3(1024), dim3(256), 0, stream>>>(chains, cur, entries);
        gather_kernel<<<dim3(1024), dim3(256), 0, stream>>>(ofs, entries, out);
    } else {
        scatter_kernel <<<dim3(1024), dim3(256), 0, stream>>>(fd, out);
        finalize_kernel<<<dim3(8192), dim3(256), 0, stream>>>(out);
    }
}

// Round 7
// 1690.552 us; speedup vs baseline: 3.1641x; 2.0707x over previous
//
#include <hip/hip_runtime.h>

#define NPIX (512 * 512)
#define NSTEPS 128
#define SRC 96
#define NOUTT (NSTEPS - SRC)            // 32
#define OSTRIDE ((size_t)NOUTT * NPIX)  // per-field output stride (floats)
#define NENT (10 * NPIX)                // total CSR entries (exactly 10 per source)

__device__ __forceinline__ float softplus_f(float z) {
    return fmaxf(z, 0.0f) + log1pf(__expf(-fabsf(z)));
}

__device__ __forceinline__ void phys_step(
    float p, float tm, float pe, float la,
    float& sn, float& ic, float& so, float& gw,
    const float* __restrict__ sW, const float* __restrict__ sb,
    float& tot, float& q1o, float& q2o, float& q3o, float& aeto)
{
    float rain = (tm > 0.0f) ? p : 0.0f;
    sn += p - rain;
    float water = rain;
    float ovf = fmaxf(ic + water - 2.0f, 0.0f);      // MAX_INT = 2.0
    ic += water - ovf;
    water = ovf;
    float melt = fminf(fmaxf(tm, 0.0f) * 3.0f, sn);  // MELT_RATE = 3.0
    sn -= melt;
    water += melt;

    const float xv[8] = {water, pe, la, tm, sn, ic, so, gw};
    float f[7];
#pragma unroll
    for (int k = 0; k < 7; ++k) {
        float z = sb[k];
#pragma unroll
        for (int c = 0; c < 8; ++c) z += xv[c] * sW[k * 8 + c];
        f[k] = softplus_f(z);
    }
    float aet = f[0], inf = f[1], per = f[2], cap = f[3];
    float q1 = f[4], q2 = f[5], q3 = f[6];

    float avail = ic + water;
    aet = fminf(aet, avail * pe);
    inf = fminf(inf, avail - aet);
    float d0 = avail + 1e-8f;
    ic    -= aet * (ic / d0);
    water -= aet * (water / d0);
    float d1 = avail - aet + 1e-8f;
    ic    -= inf * (ic / d1);
    water -= inf * (water / d1);
    per = fminf(per, so);
    cap = fminf(cap, so);
    so += inf - per - cap;
    gw += per;
    q1 = fminf(q1, water);
    q2 = fminf(q2, so);
    q3 = fminf(q3, gw);
    so -= q2;
    gw -= q3;
    tot = q1 + q2 + q3;
    sn = fmaxf(sn, 0.0f);
    ic = fmaxf(ic, 0.0f);
    so = fmaxf(so, 0.0f);
    gw = fmaxf(gw, 0.0f);
    q1o = q1; q2o = q2; q3o = q3; aeto = aet;
}

// K1: physics scan, 1 pixel/thread, next-step forcing prefetch to overlap the
// HBM load latency with the ~180-op dependent compute chain (occupancy is
// capped at 4 waves/SIMD since all 256K threads are co-resident).
__global__ void __launch_bounds__(256)
physics_kernel(const float* __restrict__ prec,
               const float* __restrict__ temp_,
               const float* __restrict__ pet_,
               const float* __restrict__ lai_,
               const float* __restrict__ Wf,
               const float* __restrict__ bf,
               float* __restrict__ out,
               int writeSeed)
{
    const int i = blockIdx.x * 256 + threadIdx.x;   // 0..NPIX-1

    __shared__ float sW[56];
    __shared__ float sb[7];
    if (threadIdx.x < 56) sW[threadIdx.x] = Wf[threadIdx.x];
    if (threadIdx.x < 7)  sb[threadIdx.x] = bf[threadIdx.x];
    __syncthreads();

    float sn = 0.0f, ic = 0.0f, so = 50.0f, gw = 100.0f;

    float p  = prec[i];
    float tm = temp_[i];
    float pe = pet_[i];
    float la = lai_[i];

    for (int t = 0; t < NSTEPS; ++t) {
        float pn = 0.f, tn = 0.f, en = 0.f, ln = 0.f;
        if (t + 1 < NSTEPS) {                       // prefetch next forcing
            const size_t off = (size_t)(t + 1) * NPIX + i;
            pn = prec[off]; tn = temp_[off]; en = pet_[off]; ln = lai_[off];
        }
        float tot, q1, q2, q3, aet;
        phys_step(p, tm, pe, la, sn, ic, so, gw, sW, sb, tot, q1, q2, q3, aet);
        if (t >= SRC) {
            float* o = out + (size_t)(t - SRC) * NPIX + i;
            o[0 * OSTRIDE] = tot;   // Q
            o[2 * OSTRIDE] = q1;
            o[3 * OSTRIDE] = q2;
            o[4 * OSTRIDE] = q3;
            o[5 * OSTRIDE] = aet;
            if (writeSeed) o[6 * OSTRIDE] = tot;   // identity seed (fallback only)
        }
        p = pn; tm = tn; pe = en; la = ln;
    }
}

// ---------- CSR build: reverse map of  A = I + sum_k coef[k] * S^(k+1) ----------
__global__ void __launch_bounds__(256)
zero_cnt(unsigned* __restrict__ cnt)
{
    cnt[blockIdx.x * 256 + threadIdx.x] = 0u;
}

__global__ void __launch_bounds__(256)
count_kernel(const int* __restrict__ fd, unsigned* __restrict__ cnt,
             unsigned* __restrict__ chains)
{
    const int i = blockIdx.x * 256 + threadIdx.x;
    bool is64 = true;                               // int64-staging detection
#pragma unroll
    for (int k = 0; k < 16; ++k) is64 = is64 && (fd[2 * k + 1] == 0);
    int d = i;
#pragma unroll
    for (int k = 0; k < 10; ++k) {
        d = is64 ? fd[2 * d] : fd[d];
        d &= (NPIX - 1);
        chains[k * NPIX + i] = (unsigned)d;
        atomicAdd(&cnt[d], 1u);
    }
}

__global__ void __launch_bounds__(256)
scan1(const unsigned* __restrict__ cnt, unsigned* __restrict__ ofs,
      unsigned* __restrict__ blk)
{
    __shared__ unsigned s[256];
    const int tid = threadIdx.x;
    const int g = blockIdx.x * 256 + tid;
    const unsigned v = cnt[g];
    s[tid] = v;
    __syncthreads();
    for (int off = 1; off < 256; off <<= 1) {
        unsigned x = (tid >= off) ? s[tid - off] : 0u;
        __syncthreads();
        s[tid] += x;
        __syncthreads();
    }
    ofs[g] = s[tid] - v;
    if (tid == 255) blk[blockIdx.x] = s[255];
}

__global__ void __launch_bounds__(256)
scan2(unsigned* __restrict__ blk)
{
    __shared__ unsigned s[256];
    const int tid = threadIdx.x;
    unsigned l0 = blk[tid * 4 + 0], l1 = blk[tid * 4 + 1];
    unsigned l2 = blk[tid * 4 + 2], l3 = blk[tid * 4 + 3];
    unsigned sum = l0 + l1 + l2 + l3;
    s[tid] = sum;
    __syncthreads();
    for (int off = 1; off < 256; off <<= 1) {
        unsigned x = (tid >= off) ? s[tid - off] : 0u;
        __syncthreads();
        s[tid] += x;
        __syncthreads();
    }
    unsigned run = s[tid] - sum;
    blk[tid * 4 + 0] = run; run += l0;
    blk[tid * 4 + 1] = run; run += l1;
    blk[tid * 4 + 2] = run; run += l2;
    blk[tid * 4 + 3] = run;
}

__global__ void __launch_bounds__(256)
scan3(unsigned* __restrict__ ofs, const unsigned* __restrict__ blk,
      unsigned* __restrict__ cur)
{
    const int g = blockIdx.x * 256 + threadIdx.x;
    const unsigned o = ofs[g] + blk[blockIdx.x];
    ofs[g] = o;
    cur[g] = o;
    if (g == 0) ofs[NPIX] = NENT;
}

__global__ void __launch_bounds__(256)
fill_kernel(const unsigned* __restrict__ chains, unsigned* __restrict__ cur,
            unsigned* __restrict__ entries)
{
    const int i = blockIdx.x * 256 + threadIdx.x;
#pragma unroll
    for (int k = 0; k < 10; ++k) {
        const unsigned d = chains[k * NPIX + i];
        const unsigned pos = atomicAdd(&cur[d], 1u);
        entries[pos] = ((unsigned)i << 4) | (unsigned)k;   // src(18b) | coefIdx(4b)
    }
}

// T1: Q [t][pix] (field 0) -> QT [pix][32t] (staged in field-1 slot).
// LDS tile 256x33 (stride-33 pad: write phase conflict-free, read phase 2-way).
__global__ void __launch_bounds__(256)
transpose_fwd(const float* __restrict__ Q, float* __restrict__ QT)
{
    __shared__ float tile[256 * 33];
    const int tix = threadIdx.x;
    const int P = blockIdx.x * 256;
    for (int t = 0; t < NOUTT; ++t)
        tile[tix * 33 + t] = Q[(size_t)t * NPIX + P + tix];
    __syncthreads();
#pragma unroll
    for (int c = 0; c < 8; ++c) {
        const int fo = tix * 4 + c * 1024;      // float offset in block's 8192
        const int pl = fo >> 5;
        const int t0 = fo & 31;
        float4 v = make_float4(tile[pl * 33 + t0],     tile[pl * 33 + t0 + 1],
                               tile[pl * 33 + t0 + 2], tile[pl * 33 + t0 + 3]);
        *(float4*)(QT + (size_t)P * 32 + fo) = v;   // coalesced 1KB/wave
    }
}

// Gather (transposed): RT[o][0..31] = QT[o][.] + sum coef[k] * QT[src][.].
// One 128B contiguous row read per entry serves ALL 32 timesteps; entries
// walked exactly once. acc statically indexed -> registers.
__global__ void __launch_bounds__(256)
gatherT_kernel(const unsigned* __restrict__ ofs, const unsigned* __restrict__ entries,
               const float* __restrict__ QT, float* __restrict__ RT)
{
    __shared__ float scoef[16];
    if (threadIdx.x < 16) {
        const float c[16] = {5.f,15.f,20.f,35.f,21.f,28.f,8.f,9.f,1.f,1.f,
                             0.f,0.f,0.f,0.f,0.f,0.f};
        scoef[threadIdx.x] = c[threadIdx.x];
    }
    __syncthreads();

    const int o = blockIdx.x * 256 + threadIdx.x;
    const unsigned s0 = ofs[o], s1 = ofs[o + 1];

    float acc[32];
    const float* qrow = QT + (size_t)o * 32;
#pragma unroll
    for (int i4 = 0; i4 < 8; ++i4) {
        float4 v = *(const float4*)(qrow + i4 * 4);     // identity term
        acc[i4 * 4 + 0] = v.x; acc[i4 * 4 + 1] = v.y;
        acc[i4 * 4 + 2] = v.z; acc[i4 * 4 + 3] = v.w;
    }
    for (unsigned j = s0; j < s1; ++j) {
        const unsigned e = entries[j];
        const float c = scoef[e & 15u];
        const float* srow = QT + (size_t)(e >> 4) * 32;
#pragma unroll
        for (int i4 = 0; i4 < 8; ++i4) {
            float4 v = *(const float4*)(srow + i4 * 4);
            acc[i4 * 4 + 0] = fmaf(c, v.x, acc[i4 * 4 + 0]);
            acc[i4 * 4 + 1] = fmaf(c, v.y, acc[i4 * 4 + 1]);
            acc[i4 * 4 + 2] = fmaf(c, v.z, acc[i4 * 4 + 2]);
            acc[i4 * 4 + 3] = fmaf(c, v.w, acc[i4 * 4 + 3]);
        }
    }
    float* rrow = RT + (size_t)o * 32;
#pragma unroll
    for (int i4 = 0; i4 < 8; ++i4)
        *(float4*)(rrow + i4 * 4) = make_float4(acc[i4 * 4 + 0], acc[i4 * 4 + 1],
                                                acc[i4 * 4 + 2], acc[i4 * 4 + 3]);
}

// T2: RT [pix][32t] (field-6 slot) -> routed [t][pix] into field 1.
__global__ void __launch_bounds__(256)
transpose_bwd(const float* __restrict__ RT, float* __restrict__ R)
{
    __shared__ float tile[256 * 33];
    const int tix = threadIdx.x;
    const int P = blockIdx.x * 256;
#pragma unroll
    for (int c = 0; c < 8; ++c) {
        const int fo = tix * 4 + c * 1024;
        const int pl = fo >> 5;
        const int t0 = fo & 31;
        float4 v = *(const float4*)(RT + (size_t)P * 32 + fo);
        tile[pl * 33 + t0]     = v.x; tile[pl * 33 + t0 + 1] = v.y;
        tile[pl * 33 + t0 + 2] = v.z; tile[pl * 33 + t0 + 3] = v.w;
    }
    __syncthreads();
    for (int t = 0; t < NOUTT; ++t)
        R[(size_t)t * NPIX + P + tix] = tile[tix * 33 + t];
}

// C: field6 = field1 (total_runoff == Q_routed), coalesced float4.
__global__ void __launch_bounds__(256)
copy_kernel(float* out)
{
    const size_t idx = ((size_t)blockIdx.x * 256 + threadIdx.x) * 4;
    const float4 r = *(const float4*)(out + 1 * OSTRIDE + idx);
    *(float4*)(out + 6 * OSTRIDE + idx) = r;
}

// ---------- fallback path (proven correct in round 5) ----------
__global__ void __launch_bounds__(256)
scatter_kernel(const int* __restrict__ fd, float* out)
{
    const int i = blockIdx.x * 256 + threadIdx.x;
    bool is64 = true;
#pragma unroll
    for (int k = 0; k < 16; ++k) is64 = is64 && (fd[2 * k + 1] == 0);
    int dest[10];
    int d = i;
#pragma unroll
    for (int k = 0; k < 10; ++k) {
        d = is64 ? fd[2 * d] : fd[d];
        d &= (NPIX - 1);
        dest[k] = d;
    }
    const float coef[10] = {5.f, 15.f, 20.f, 35.f, 21.f, 28.f, 8.f, 9.f, 1.f, 1.f};
    const float* Q  = out;
    float*       RT = out + 6 * OSTRIDE;
    for (int t = 0; t < NOUTT; ++t) {
        const float tv = Q[(size_t)t * NPIX + i];
#pragma unroll
        for (int k = 0; k < 10; ++k)
            atomicAdd(&RT[(size_t)t * NPIX + dest[k]], coef[k] * tv);
    }
}

__global__ void __launch_bounds__(256)
finalize_kernel(float* out)
{
    const size_t idx = ((size_t)blockIdx.x * 256 + threadIdx.x) * 4;
    const float4 r = *(const float4*)(out + 6 * OSTRIDE + idx);
    *(float4*)(out + 1 * OSTRIDE + idx) = r;
}

extern "C" void kernel_launch(void* const* d_in, const int* in_sizes, int n_in,
                              void* d_out, int out_size, void* d_ws, size_t ws_size,
                              hipStream_t stream)
{
    const float* prec  = (const float*)d_in[0];
    const float* temp_ = (const float*)d_in[1];
    const float* pet_  = (const float*)d_in[2];
    const float* lai_  = (const float*)d_in[3];
    const float* Wf    = (const float*)d_in[4];
    const float* bf    = (const float*)d_in[5];
    const int*   fd    = (const int*)d_in[6];
    float* out = (float*)d_out;

    // ws layout (u32): cnt[NPIX] | cur[NPIX] | ofs[NPIX+16] | blk[1024]
    //                  | chains[NENT] | entries[NENT]   ~= 23 MB
    const size_t need = (size_t)(NPIX * 3 + 16 + 1024 + 2 * NENT) * sizeof(unsigned);
    const bool useGather = (ws_size >= need);

    physics_kernel<<<dim3(1024), dim3(256), 0, stream>>>(
        prec, temp_, pet_, lai_, Wf, bf, out, useGather ? 0 : 1);

    if (useGather) {
        unsigned* cnt     = (unsigned*)d_ws;
        unsigned* cur     = cnt + NPIX;
        unsigned* ofs     = cur + NPIX;
        unsigned* blk     = ofs + NPIX + 16;
        unsigned* chains  = blk + 1024;
        unsigned* entries = chains + NENT;
        float* QT = out + 1 * OSTRIDE;   // field-1 slot as Q-transpose scratch
        float* RT = out + 6 * OSTRIDE;   // field-6 slot as routed-transpose scratch

        zero_cnt     <<<dim3(1024), dim3(256), 0, stream>>>(cnt);
        count_kernel <<<dim3(1024), dim3(256), 0, stream>>>(fd, cnt, chains);
        scan1        <<<dim3(1024), dim3(256), 0, stream>>>(cnt, ofs, blk);
        scan2        <<<dim3(1),    dim3(256), 0, stream>>>(blk);
        scan3        <<<dim3(1024), dim3(256), 0, stream>>>(ofs, blk, cur);
        fill_kernel  <<<dim3(1024), dim3(256), 0, stream>>>(chains, cur, entries);
        transpose_fwd<<<dim3(1024), dim3(256), 0, stream>>>(out, QT);
        gatherT_kernel<<<dim3(1024), dim3(256), 0, stream>>>(ofs, entries, QT, RT);
        transpose_bwd<<<dim3(1024), dim3(256), 0, stream>>>(RT, out + 1 * OSTRIDE);
        copy_kernel  <<<dim3(8192), dim3(256), 0, stream>>>(out);
    } else {
        scatter_kernel <<<dim3(1024), dim3(256), 0, stream>>>(fd, out);
        finalize_kernel<<<dim3(8192), dim3(256), 0, stream>>>(out);
    }
}